// Round 6
// baseline (327.010 us; speedup 1.0000x reference)
//
#include <hip/hip_runtime.h>
#include <hip/hip_bf16.h>

#define B_   2
#define N_   2048
#define DIM_ 1024
#define HD_  64
#define DV_  128

typedef __bf16 bf16;
typedef __bf16 bf16x8 __attribute__((ext_vector_type(8)));
typedef __bf16 bf16x4 __attribute__((ext_vector_type(4)));
typedef float  floatx4 __attribute__((ext_vector_type(4)));
typedef float  floatx16 __attribute__((ext_vector_type(16)));
typedef unsigned int uint;
typedef uint uint2v __attribute__((ext_vector_type(2)));
typedef uint uint4v __attribute__((ext_vector_type(4)));

#if __has_builtin(__builtin_amdgcn_exp2f)
#define EXP2(x) __builtin_amdgcn_exp2f(x)
#else
#define EXP2(x) exp2f(x)
#endif

// Q scale: hd^-0.5 (=1/8) with log2(e) folded in so softmax uses raw v_exp_f32 (2^x).
#define QSCALE 0.1803368801111244f

__device__ __forceinline__ void async16(const void* g, void* l) {
  __builtin_amdgcn_global_load_lds(
      (__attribute__((address_space(1))) void*)g,
      (__attribute__((address_space(3))) void*)l, 16, 0, 0);
}

__device__ __forceinline__ uint packbf(float a, float b) {
  unsigned short ul = __builtin_bit_cast(unsigned short, (bf16)a);
  unsigned short uh = __builtin_bit_cast(unsigned short, (bf16)b);
  return (uint)ul | ((uint)uh << 16);
}

// ---------------- convert fp32 -> bf16 (x + 4 weights, contiguous dst) ----------------
__global__ void convert_kernel(const float* __restrict__ x,
                               const float* __restrict__ wq,
                               const float* __restrict__ wk,
                               const float* __restrict__ wv,
                               const float* __restrict__ wo,
                               bf16* __restrict__ dst) {
  const int NX = B_ * N_ * DIM_;   // 4194304
  const int NW = DIM_ * DIM_;      // 1048576 = 2^20
  int i = (blockIdx.x * 256 + threadIdx.x) * 4;
  const float* src;
  int off;
  if (i < NX) { src = x; off = i; }
  else {
    int j = i - NX;
    int w = j >> 20;
    off = j & (NW - 1);
    src = (w == 0) ? wq : (w == 1) ? wk : (w == 2) ? wv : wo;
  }
  float4 v = *(const float4*)(src + off);
  bf16x4 o = { (bf16)v.x, (bf16)v.y, (bf16)v.z, (bf16)v.w };
  *(bf16x4*)(dst + i) = o;
}

// ---------------- QKV projection GEMM (z=0:Q, 1:K, 2:V-transposed) ----------------
// R6 version (256 threads, 128x128 tiles): best measured config.
__global__ __launch_bounds__(256) void proj_kernel(
    const bf16* __restrict__ xb, const bf16* __restrict__ wall,
    const float* __restrict__ bq, const float* __restrict__ bk,
    const float* __restrict__ bv,
    bf16* __restrict__ qo, bf16* __restrict__ ko, bf16* __restrict__ vt) {
  __shared__ __align__(16) bf16 SM[2 * 128 * 64];  // At | Bt; reused as V^T tile
  bf16* At = SM;
  bf16* Bt = SM + 128 * 64;
  const int tid = threadIdx.x, lane = tid & 63, w = tid >> 6;
  const int tm = blockIdx.x, tn = blockIdx.y, z = blockIdx.z;
  const int quad = lane >> 4, l15 = lane & 15;
  const int wm = (w >> 1) * 64, wn = (w & 1) * 64;
  const bf16* Ab = xb + (long)tm * 128 * DIM_;
  const bf16* Bb = wall + (long)z * (DIM_ * DIM_) + (long)tn * 128 * DIM_;
  floatx4 zero = {0.f, 0.f, 0.f, 0.f};
  floatx4 acc[4][4];
#pragma unroll
  for (int i = 0; i < 4; ++i)
#pragma unroll
    for (int j = 0; j < 4; ++j) acc[i][j] = zero;

  for (int kb = 0; kb < DIM_ / 64; ++kb) {
    for (int idx = tid; idx < 1024; idx += 256) {
      int row = idx >> 3, ch = idx & 7, g = ch ^ (row & 7);
      async16(Ab + row * DIM_ + kb * 64 + g * 8, (char*)At + (idx - lane) * 16);
      async16(Bb + row * DIM_ + kb * 64 + g * 8, (char*)Bt + (idx - lane) * 16);
    }
    __syncthreads();
#pragma unroll
    for (int ks = 0; ks < 2; ++ks) {
      bf16x8 af[4], bfm[4];
#pragma unroll
      for (int mt = 0; mt < 4; ++mt) {
        int r = wm + mt * 16 + l15;
        af[mt] = *(const bf16x8*)&At[r * 64 + ((ks * 4 + quad) ^ (r & 7)) * 8];
      }
#pragma unroll
      for (int nt = 0; nt < 4; ++nt) {
        int r = wn + nt * 16 + l15;
        bfm[nt] = *(const bf16x8*)&Bt[r * 64 + ((ks * 4 + quad) ^ (r & 7)) * 8];
      }
#pragma unroll
      for (int mt = 0; mt < 4; ++mt)
#pragma unroll
        for (int nt = 0; nt < 4; ++nt)
          acc[mt][nt] = __builtin_amdgcn_mfma_f32_16x16x32_bf16(
              af[mt], bfm[nt], acc[mt][nt], 0, 0, 0);
    }
    __syncthreads();
  }

  if (z != 2) {
#pragma unroll
    for (int mt = 0; mt < 4; ++mt)
#pragma unroll
      for (int nt = 0; nt < 4; ++nt)
#pragma unroll
        for (int r = 0; r < 4; ++r) {
          int grow = tm * 128 + wm + mt * 16 + quad * 4 + r;
          int gcol = tn * 128 + wn + nt * 16 + l15;
          float v = acc[mt][nt][r];
          if (z == 0) {
            qo[(long)grow * DIM_ + gcol] = (bf16)((v + bq[gcol]) * QSCALE);
          } else {
            ko[(long)grow * DIM_ + gcol] = (bf16)(v + bk[gcol]);
          }
        }
  } else {
    // V epilogue: transpose through LDS, coalesced V^T row stores.
    bf16* Vl = SM;
#pragma unroll
    for (int nt = 0; nt < 4; ++nt) {
      int d = wn + nt * 16 + l15;
      float bvv = bv[tn * 128 + d];
      int m = (d & 7) * 2;
#pragma unroll
      for (int mt = 0; mt < 4; ++mt) {
        bf16x4 v4 = { (bf16)(acc[mt][nt][0] + bvv), (bf16)(acc[mt][nt][1] + bvv),
                      (bf16)(acc[mt][nt][2] + bvv), (bf16)(acc[mt][nt][3] + bvv) };
        int c = (wm >> 2) + mt * 4 + quad;
        *(bf16x4*)&Vl[d * 128 + (c ^ m) * 4] = v4;
      }
    }
    __syncthreads();
    const int bb = tm >> 4, e = tn;
    const long rowbase = ((long)(bb * 8 + e) * 128) * (long)N_ + (tm & 15) * 128;
#pragma unroll
    for (int p = 0; p < 8; ++p) {
      int d = p * 16 + (tid >> 4), j = tid & 15;
      int cs = (2 * j) ^ ((d & 7) * 2);
      bf16x8 val = *(const bf16x8*)&Vl[d * 128 + cs * 4];
      *(bf16x8*)&vt[rowbase + (long)d * N_ + j * 8] = val;
    }
  }
}

// ---------------- fused pair flash attention + diff + RMSNorm (32x32 MFMA) ------------
// R15: stage-free attention. R10 (62.7us) = LDS stage + barrier lockstep; R11/
// R12/R14 variants of that machinery all regressed. K/V is L2-resident (1MB
// per (e,b) pair, 16 blocks share it), so per guide m169 ("stage only when
// data doesn't cache-fit", +26% measured) fragments are now read DIRECTLY from
// global through L1/L2: no global_load_lds, no k-loop barriers, no vmcnt
// drains. Waves free-run and decorrelate phases (the gain R14 chased);
// setprio now acts in its m191-proven independent-wave regime. All 8 waves
// read identical V lines -> L1 broadcast; per-CU unique traffic unchanged
// (32KB/iter). XCD-bijective block swizzle (256%8==0) pins each (e,b) pair's
// 16 blocks to one XCD: 2MB working set per 4MB XCD-L2. LDS = 64KB epilogue
// exchange only. lam computed in epilogue (no lam_kernel launch).
__global__ __launch_bounds__(512, 2) void attn_kernel(
    const bf16* __restrict__ qb, const bf16* __restrict__ kbuf,
    const bf16* __restrict__ vt,
    const float* __restrict__ lq1, const float* __restrict__ lk1,
    const float* __restrict__ lq2, const float* __restrict__ lk2,
    const float* __restrict__ norm_w, bf16* __restrict__ ao) {
  __shared__ __align__(16) float Ob[128 * 128];  // epilogue exchange only

  const int tid = threadIdx.x, lane = tid & 63, w = tid >> 6;
  // XCD-bijective swizzle: XCD i (= blockIdx.x % 8) gets (e,b)-pairs {2i,2i+1}.
  const int swz = (blockIdx.x & 7) * 32 + (blockIdx.x >> 3);
  const int qt = swz & 15, e = (swz >> 4) & 7, b = swz >> 7;
  const int hl = w & 1, qh = w >> 1;     // qh in [0,4): 32-query strip
  const int h = lane >> 5, l31 = lane & 31;
  const int qbase = qt * 128;

  // Q fragments (B-operand: B[n=q=l31][k=c*16+8h+j]), loop-invariant, from global.
  bf16x8 qf[4];
  {
    const bf16* qrp = qb + (long)(b * N_ + qbase + qh * 32 + l31) * DIM_
                      + e * 128 + hl * 64 + h * 8;
#pragma unroll
    for (int c = 0; c < 4; ++c) qf[c] = *(const bf16x8*)(qrp + c * 16);
  }

  // Per-lane K row pointer: row = kt*64 + kt2*32 + l31 of head (e,hl).
  const bf16* krow = kbuf + (long)b * N_ * DIM_ + (long)l31 * DIM_
                     + e * 128 + hl * 64 + h * 8;
  // Per-lane V^T row pointer: row d = dt*32 + l31.
  const bf16* vrow = vt + (long)(b * 8 + e) * DV_ * N_ + (long)l31 * N_ + h * 8;

  floatx16 acc[4];
#pragma unroll
  for (int dt = 0; dt < 4; ++dt) acc[dt] = floatx16{};
  float lp = 0.f;  // per-lane row-sum partial, q = l31

  for (int kt = 0; kt < N_ / 64; ++kt) {
    // fragments straight from global (L1/L2-resident tile)
    bf16x8 kfrag[2][4], vfrag[4][4];
    const bf16* kp = krow + (long)kt * 64 * DIM_;
#pragma unroll
    for (int kt2 = 0; kt2 < 2; ++kt2)
#pragma unroll
      for (int c = 0; c < 4; ++c)
        kfrag[kt2][c] = *(const bf16x8*)(kp + (long)kt2 * 32 * DIM_ + c * 16);
    const bf16* vp = vrow + kt * 64;
#pragma unroll
    for (int dt = 0; dt < 4; ++dt)
#pragma unroll
      for (int kc = 0; kc < 4; ++kc)
        vfrag[dt][kc] = *(const bf16x8*)(vp + (long)dt * 32 * N_ + kc * 16);

    bf16x8 af[2][2];
#pragma unroll
    for (int kt2 = 0; kt2 < 2; ++kt2) {
      floatx16 sv{};
      __builtin_amdgcn_s_setprio(1);
#pragma unroll
      for (int c = 0; c < 4; ++c)
        sv = __builtin_amdgcn_mfma_f32_32x32x16_bf16(kfrag[kt2][c], qf[c], sv, 0, 0, 0);
      __builtin_amdgcn_s_setprio(0);
      // exp2 + row-sum
      float t[16];
      float s = 0.f;
#pragma unroll
      for (int i = 0; i < 16; ++i) { t[i] = EXP2(sv[i]); s += t[i]; }
      lp += s;
      // pack: d_i = 2 consecutive keys (reg pairs); key(reg) = (reg&3)+8*(reg>>2)+4h
      uint d0 = packbf(t[0], t[1]),   d1 = packbf(t[2], t[3]);
      uint d2 = packbf(t[4], t[5]),   d3 = packbf(t[6], t[7]);
      uint d4 = packbf(t[8], t[9]),   d5 = packbf(t[10], t[11]);
      uint d6 = packbf(t[12], t[13]), d7 = packbf(t[14], t[15]);
      uint4v f0, f1;
#if __has_builtin(__builtin_amdgcn_permlane32_swap)
      uint2v r02 = __builtin_amdgcn_permlane32_swap(d0, d2, false, false);
      uint2v r13 = __builtin_amdgcn_permlane32_swap(d1, d3, false, false);
      f0 = uint4v{r02.x, r13.x, r02.y, r13.y};
      uint2v r46 = __builtin_amdgcn_permlane32_swap(d4, d6, false, false);
      uint2v r57 = __builtin_amdgcn_permlane32_swap(d5, d7, false, false);
      f1 = uint4v{r46.x, r57.x, r46.y, r57.y};
#else
      uint e0 = __shfl_xor((int)d0, 32, 64), e1 = __shfl_xor((int)d1, 32, 64);
      uint e2 = __shfl_xor((int)d2, 32, 64), e3 = __shfl_xor((int)d3, 32, 64);
      uint e4 = __shfl_xor((int)d4, 32, 64), e5 = __shfl_xor((int)d5, 32, 64);
      uint e6 = __shfl_xor((int)d6, 32, 64), e7 = __shfl_xor((int)d7, 32, 64);
      f0 = h ? uint4v{e2, e3, d2, d3} : uint4v{d0, d1, e0, e1};
      f1 = h ? uint4v{e6, e7, d6, d7} : uint4v{d4, d5, e4, e5};
#endif
      af[kt2][0] = __builtin_bit_cast(bf16x8, f0);
      af[kt2][1] = __builtin_bit_cast(bf16x8, f1);
    }
    // O += P @ V : A = P[q=l31][k=key], B = V^T[d=l31][k=key]
    __builtin_amdgcn_s_setprio(1);
#pragma unroll
    for (int dt = 0; dt < 4; ++dt)
#pragma unroll
      for (int kt2 = 0; kt2 < 2; ++kt2)
#pragma unroll
        for (int u = 0; u < 2; ++u)
          acc[dt] = __builtin_amdgcn_mfma_f32_32x32x16_bf16(
              af[kt2][u], vfrag[dt][kt2 * 2 + u], acc[dt], 0, 0, 0);
    __builtin_amdgcn_s_setprio(0);
  }

  // full row-sums (both lane halves hold all keys' partials for q=l31)
  lp += __shfl_xor(lp, 32, 64);

  if (hl == 1) {
#pragma unroll
    for (int r = 0; r < 16; ++r) {
      int qloc = (r & 3) + 8 * (r >> 2) + 4 * h;
      float inv = 1.0f / __shfl(lp, qloc, 64);
      float* row = &Ob[(qh * 32 + qloc) * 128 + l31];
#pragma unroll
      for (int dt = 0; dt < 4; ++dt) row[dt * 32] = acc[dt][r] * inv;
    }
  }
  __syncthreads();
  if (hl == 0) {
    // lambda = exp(lq1.lk1) - exp(lq2.lk2) + 0.8, computed in-wave (64 lanes).
    float la = lq1[lane] * lk1[lane];
    float lb = lq2[lane] * lk2[lane];
#pragma unroll
    for (int m = 1; m < 64; m <<= 1) {
      la += __shfl_xor(la, m, 64);
      lb += __shfl_xor(lb, m, 64);
    }
    float lam = __expf(la) - __expf(lb) + 0.8f;
    float nw4[4];
#pragma unroll
    for (int dt = 0; dt < 4; ++dt) nw4[dt] = norm_w[dt * 32 + l31] * 0.2f;
#pragma unroll
    for (int r = 0; r < 16; ++r) {
      int qloc = (r & 3) + 8 * (r >> 2) + 4 * h;
      float inv = 1.0f / __shfl(lp, qloc, 64);
      const float* row = &Ob[(qh * 32 + qloc) * 128 + l31];
      float v[4], ss = 0.f;
#pragma unroll
      for (int dt = 0; dt < 4; ++dt) {
        v[dt] = acc[dt][r] * inv - lam * row[dt * 32];
        ss += v[dt] * v[dt];
      }
#pragma unroll
      for (int msk = 1; msk < 32; msk <<= 1) ss += __shfl_xor(ss, msk, 64);
      float rms = rsqrtf(ss * (1.0f / 128.0f) + 1e-5f);
      int n = qbase + qh * 32 + qloc;
      bf16* dst = ao + (long)(b * N_ + n) * DIM_ + e * DV_ + l31;
#pragma unroll
      for (int dt = 0; dt < 4; ++dt) dst[dt * 32] = (bf16)(v[dt] * rms * nw4[dt]);
    }
  }
}

// ---------------- output projection GEMM -> fp32 ----------------
// 128x128 tile kept (A/B reuse), but 512 threads = 8 waves (wave 32x64):
// 2 waves/SIMD at grid 256 vs R6's 1 wave/SIMD — isolated occupancy fix.
__global__ __launch_bounds__(512) void out_gemm(
    const bf16* __restrict__ ab, const bf16* __restrict__ wo,
    const float* __restrict__ bo, float* __restrict__ out) {
  __shared__ __align__(16) bf16 At[128 * 64];
  __shared__ __align__(16) bf16 Bt[128 * 64];
  const int tid = threadIdx.x, lane = tid & 63, w = tid >> 6;
  const int tm = blockIdx.x, tn = blockIdx.y;
  const int quad = lane >> 4, l15 = lane & 15;
  const int wm = (w & 3) * 32, wn = (w >> 2) * 64;
  const bf16* Ab = ab + (long)tm * 128 * DIM_;
  const bf16* Bb = wo + (long)tn * 128 * DIM_;
  floatx4 zero = {0.f, 0.f, 0.f, 0.f};
  floatx4 acc[2][4];
#pragma unroll
  for (int i = 0; i < 2; ++i)
#pragma unroll
    for (int j = 0; j < 4; ++j) acc[i][j] = zero;

  for (int kb = 0; kb < DIM_ / 64; ++kb) {
    for (int idx = tid; idx < 1024; idx += 512) {
      int row = idx >> 3, ch = idx & 7, g = ch ^ (row & 7);
      async16(Ab + row * DIM_ + kb * 64 + g * 8, (char*)At + (idx - lane) * 16);
      async16(Bb + row * DIM_ + kb * 64 + g * 8, (char*)Bt + (idx - lane) * 16);
    }
    __syncthreads();
#pragma unroll
    for (int ks = 0; ks < 2; ++ks) {
      bf16x8 af[2], bfm[4];
#pragma unroll
      for (int mt = 0; mt < 2; ++mt) {
        int r = wm + mt * 16 + l15;
        af[mt] = *(const bf16x8*)&At[r * 64 + ((ks * 4 + quad) ^ (r & 7)) * 8];
      }
#pragma unroll
      for (int nt = 0; nt < 4; ++nt) {
        int r = wn + nt * 16 + l15;
        bfm[nt] = *(const bf16x8*)&Bt[r * 64 + ((ks * 4 + quad) ^ (r & 7)) * 8];
      }
#pragma unroll
      for (int mt = 0; mt < 2; ++mt)
#pragma unroll
        for (int nt = 0; nt < 4; ++nt)
          acc[mt][nt] = __builtin_amdgcn_mfma_f32_16x16x32_bf16(
              af[mt], bfm[nt], acc[mt][nt], 0, 0, 0);
    }
    __syncthreads();
  }
#pragma unroll
  for (int mt = 0; mt < 2; ++mt)
#pragma unroll
    for (int nt = 0; nt < 4; ++nt)
#pragma unroll
      for (int r = 0; r < 4; ++r) {
        int grow = tm * 128 + wm + mt * 16 + quad * 4 + r;
        int gcol = tn * 128 + wn + nt * 16 + l15;
        out[(long)grow * DIM_ + gcol] = acc[mt][nt][r] + bo[gcol];
      }
}

extern "C" void kernel_launch(void* const* d_in, const int* in_sizes, int n_in,
                              void* d_out, int out_size, void* d_ws, size_t ws_size,
                              hipStream_t stream) {
  const float* x    = (const float*)d_in[0];
  const float* Wq   = (const float*)d_in[1];
  const float* bq   = (const float*)d_in[2];
  const float* Wk   = (const float*)d_in[3];
  const float* bk   = (const float*)d_in[4];
  const float* Wv   = (const float*)d_in[5];
  const float* bv   = (const float*)d_in[6];
  const float* Wo   = (const float*)d_in[7];
  const float* bo   = (const float*)d_in[8];
  const float* nw   = (const float*)d_in[9];
  const float* lq1  = (const float*)d_in[10];
  const float* lk1  = (const float*)d_in[11];
  const float* lq2  = (const float*)d_in[12];
  const float* lk2  = (const float*)d_in[13];

  char* ws = (char*)d_ws;
  bf16* xb   = (bf16*)(ws + 256);              // [4096,1024] bf16
  bf16* wqb  = xb + 4194304;                   // Wq,Wk,Wv,Wo bf16 contiguous
  bf16* qb   = wqb + 4 * 1048576;              // Q scaled  [4096,1024]
  bf16* kbuf = qb + 4194304;                   // K         [4096,1024]
  bf16* vtb  = kbuf + 4194304;                 // V^T [b,e,d,key] = [16,128,2048]
  bf16* ab   = vtb + 4194304;                  // attn out  [4096,1024]

  convert_kernel<<<8192, 256, 0, stream>>>(x, Wq, Wk, Wv, Wo, xb);
  proj_kernel<<<dim3(32, 8, 3), 256, 0, stream>>>(xb, wqb, bq, bk, bv, qb, kbuf, vtb);
  attn_kernel<<<256, 512, 0, stream>>>(qb, kbuf, vtb, lq1, lk1, lq2, lk2, nw, ab);
  out_gemm<<<dim3(32, 8), 512, 0, stream>>>(ab, wqb + 3 * 1048576, bo, (float*)d_out);
}

// Round 7
// 209.440 us; speedup vs baseline: 1.5614x; 1.5614x over previous
//
#include <hip/hip_runtime.h>
#include <hip/hip_bf16.h>

#define B_   2
#define N_   2048
#define DIM_ 1024
#define HD_  64
#define DV_  128

typedef __bf16 bf16;
typedef __bf16 bf16x8 __attribute__((ext_vector_type(8)));
typedef __bf16 bf16x4 __attribute__((ext_vector_type(4)));
typedef float  floatx4 __attribute__((ext_vector_type(4)));
typedef float  floatx16 __attribute__((ext_vector_type(16)));
typedef unsigned int uint;
typedef uint uint2v __attribute__((ext_vector_type(2)));
typedef uint uint4v __attribute__((ext_vector_type(4)));

#if __has_builtin(__builtin_amdgcn_exp2f)
#define EXP2(x) __builtin_amdgcn_exp2f(x)
#else
#define EXP2(x) exp2f(x)
#endif

// Q scale: hd^-0.5 (=1/8) with log2(e) folded in so softmax uses raw v_exp_f32 (2^x).
#define QSCALE 0.1803368801111244f

__device__ __forceinline__ void async16(const void* g, void* l) {
  __builtin_amdgcn_global_load_lds(
      (__attribute__((address_space(1))) void*)g,
      (__attribute__((address_space(3))) void*)l, 16, 0, 0);
}

__device__ __forceinline__ uint packbf(float a, float b) {
  unsigned short ul = __builtin_bit_cast(unsigned short, (bf16)a);
  unsigned short uh = __builtin_bit_cast(unsigned short, (bf16)b);
  return (uint)ul | ((uint)uh << 16);
}

// ---------------- convert fp32 -> bf16 (x + 4 weights, contiguous dst) ----------------
__global__ void convert_kernel(const float* __restrict__ x,
                               const float* __restrict__ wq,
                               const float* __restrict__ wk,
                               const float* __restrict__ wv,
                               const float* __restrict__ wo,
                               bf16* __restrict__ dst) {
  const int NX = B_ * N_ * DIM_;   // 4194304
  const int NW = DIM_ * DIM_;      // 1048576 = 2^20
  int i = (blockIdx.x * 256 + threadIdx.x) * 4;
  const float* src;
  int off;
  if (i < NX) { src = x; off = i; }
  else {
    int j = i - NX;
    int w = j >> 20;
    off = j & (NW - 1);
    src = (w == 0) ? wq : (w == 1) ? wk : (w == 2) ? wv : wo;
  }
  float4 v = *(const float4*)(src + off);
  bf16x4 o = { (bf16)v.x, (bf16)v.y, (bf16)v.z, (bf16)v.w };
  *(bf16x4*)(dst + i) = o;
}

// ---------------- QKV projection GEMM (z=0:Q, 1:K, 2:V-transposed) ----------------
// R6 version (256 threads, 128x128 tiles): best measured config.
__global__ __launch_bounds__(256) void proj_kernel(
    const bf16* __restrict__ xb, const bf16* __restrict__ wall,
    const float* __restrict__ bq, const float* __restrict__ bk,
    const float* __restrict__ bv,
    bf16* __restrict__ qo, bf16* __restrict__ ko, bf16* __restrict__ vt) {
  __shared__ __align__(16) bf16 SM[2 * 128 * 64];  // At | Bt; reused as V^T tile
  bf16* At = SM;
  bf16* Bt = SM + 128 * 64;
  const int tid = threadIdx.x, lane = tid & 63, w = tid >> 6;
  const int tm = blockIdx.x, tn = blockIdx.y, z = blockIdx.z;
  const int quad = lane >> 4, l15 = lane & 15;
  const int wm = (w >> 1) * 64, wn = (w & 1) * 64;
  const bf16* Ab = xb + (long)tm * 128 * DIM_;
  const bf16* Bb = wall + (long)z * (DIM_ * DIM_) + (long)tn * 128 * DIM_;
  floatx4 zero = {0.f, 0.f, 0.f, 0.f};
  floatx4 acc[4][4];
#pragma unroll
  for (int i = 0; i < 4; ++i)
#pragma unroll
    for (int j = 0; j < 4; ++j) acc[i][j] = zero;

  for (int kb = 0; kb < DIM_ / 64; ++kb) {
    for (int idx = tid; idx < 1024; idx += 256) {
      int row = idx >> 3, ch = idx & 7, g = ch ^ (row & 7);
      async16(Ab + row * DIM_ + kb * 64 + g * 8, (char*)At + (idx - lane) * 16);
      async16(Bb + row * DIM_ + kb * 64 + g * 8, (char*)Bt + (idx - lane) * 16);
    }
    __syncthreads();
#pragma unroll
    for (int ks = 0; ks < 2; ++ks) {
      bf16x8 af[4], bfm[4];
#pragma unroll
      for (int mt = 0; mt < 4; ++mt) {
        int r = wm + mt * 16 + l15;
        af[mt] = *(const bf16x8*)&At[r * 64 + ((ks * 4 + quad) ^ (r & 7)) * 8];
      }
#pragma unroll
      for (int nt = 0; nt < 4; ++nt) {
        int r = wn + nt * 16 + l15;
        bfm[nt] = *(const bf16x8*)&Bt[r * 64 + ((ks * 4 + quad) ^ (r & 7)) * 8];
      }
#pragma unroll
      for (int mt = 0; mt < 4; ++mt)
#pragma unroll
        for (int nt = 0; nt < 4; ++nt)
          acc[mt][nt] = __builtin_amdgcn_mfma_f32_16x16x32_bf16(
              af[mt], bfm[nt], acc[mt][nt], 0, 0, 0);
    }
    __syncthreads();
  }

  if (z != 2) {
#pragma unroll
    for (int mt = 0; mt < 4; ++mt)
#pragma unroll
      for (int nt = 0; nt < 4; ++nt)
#pragma unroll
        for (int r = 0; r < 4; ++r) {
          int grow = tm * 128 + wm + mt * 16 + quad * 4 + r;
          int gcol = tn * 128 + wn + nt * 16 + l15;
          float v = acc[mt][nt][r];
          if (z == 0) {
            qo[(long)grow * DIM_ + gcol] = (bf16)((v + bq[gcol]) * QSCALE);
          } else {
            ko[(long)grow * DIM_ + gcol] = (bf16)(v + bk[gcol]);
          }
        }
  } else {
    // V epilogue: transpose through LDS, coalesced V^T row stores.
    bf16* Vl = SM;
#pragma unroll
    for (int nt = 0; nt < 4; ++nt) {
      int d = wn + nt * 16 + l15;
      float bvv = bv[tn * 128 + d];
      int m = (d & 7) * 2;
#pragma unroll
      for (int mt = 0; mt < 4; ++mt) {
        bf16x4 v4 = { (bf16)(acc[mt][nt][0] + bvv), (bf16)(acc[mt][nt][1] + bvv),
                      (bf16)(acc[mt][nt][2] + bvv), (bf16)(acc[mt][nt][3] + bvv) };
        int c = (wm >> 2) + mt * 4 + quad;
        *(bf16x4*)&Vl[d * 128 + (c ^ m) * 4] = v4;
      }
    }
    __syncthreads();
    const int bb = tm >> 4, e = tn;
    const long rowbase = ((long)(bb * 8 + e) * 128) * (long)N_ + (tm & 15) * 128;
#pragma unroll
    for (int p = 0; p < 8; ++p) {
      int d = p * 16 + (tid >> 4), j = tid & 15;
      int cs = (2 * j) ^ ((d & 7) * 2);
      bf16x8 val = *(const bf16x8*)&Vl[d * 128 + cs * 4];
      *(bf16x8*)&vt[rowbase + (long)d * N_ + j * 8] = val;
    }
  }
}

// ---------------- fused pair flash attention + diff + RMSNorm (32x32 MFMA) ------------
// R16: consolidation. R10 (512 thr, 8 waves, wave = 32q x 1 head x all keys,
// double-buffered LDS stage + one barrier/iter) measured 62.7us — every
// structural departure regressed for a measured reason:
//   R11 16 lockstep waves: pipe collision, 73us. R12 64q/wave: 117us.
//   R14 2 small blocks/CU: staging doubled, 75.6us. R15 no staging: 2KB-stride
//   gathers hit the L1 line-fetch wall (MfmaUtil 11%, 190us).
// So: R10 inner loop byte-identical. One surviving change from R14/R15 (both
// passed correctness): lambda computed in-epilogue, lam_kernel launch removed.
__global__ __launch_bounds__(512, 2) void attn_kernel(
    const bf16* __restrict__ qb, const bf16* __restrict__ kbuf,
    const bf16* __restrict__ vt,
    const float* __restrict__ lq1, const float* __restrict__ lk1,
    const float* __restrict__ lq2, const float* __restrict__ lk2,
    const float* __restrict__ norm_w, bf16* __restrict__ ao) {
  __shared__ __align__(16) char smem[65536];
  // K buf: smem + buf*16384          [2 heads][64 keys][64 hd] bf16, 16 KB/buf
  // V buf: smem + 32768 + buf*16384  [128 d][64 keys] bf16, 16 KB/buf
  // Ob   : overlays everything after the k-loop: [128 q][128 d] fp32, 64 KB

  const int tid = threadIdx.x, lane = tid & 63, w = tid >> 6;
  const int qt = blockIdx.x, e = blockIdx.y, b = blockIdx.z;
  const int hl = w & 1, qh = w >> 1;     // qh in [0,4): 32-query strip
  const int h = lane >> 5, l31 = lane & 31;
  const int qbase = qt * 128;

  // Q fragments (B-operand: B[n=q=l31][k=c*16+8h+j]), loop-invariant, from global.
  bf16x8 qf[4];
  {
    const bf16* qrp = qb + (long)(b * N_ + qbase + qh * 32 + l31) * DIM_
                      + e * 128 + hl * 64 + h * 8;
#pragma unroll
    for (int c = 0; c < 4; ++c) qf[c] = *(const bf16x8*)(qrp + c * 16);
  }

  const bf16* kbase = kbuf + (long)b * N_ * DIM_ + e * 128;
  const bf16* vbase = vt + (long)(b * 8 + e) * DV_ * N_;

  floatx16 acc[4];
#pragma unroll
  for (int dt = 0; dt < 4; ++dt) acc[dt] = floatx16{};
  float lp = 0.f;  // per-lane row-sum partial, q = l31

#define STAGE(ktv, bufv)                                                            \
  {                                                                                 \
    int kt_ = (ktv);                                                                \
    char* kdst = smem + (bufv) * 16384;                                             \
    char* vdst = smem + 32768 + (bufv) * 16384;                                     \
    _Pragma("unroll") for (int t = 0; t < 2; ++t) {                                 \
      int idx = tid + t * 512;                                                      \
      int khl = idx >> 9, row = (idx >> 3) & 63, ch = idx & 7;                      \
      int g = ch ^ (row & 7) ^ ((row >> 3) & 3);                                    \
      async16(kbase + ((long)(kt_ * 64 + row)) * DIM_ + khl * 64 + g * 8,           \
              kdst + (idx - lane) * 16);                                            \
    }                                                                               \
    _Pragma("unroll") for (int t = 0; t < 2; ++t) {                                 \
      int idx = tid + t * 512;                                                      \
      int row = idx >> 3, ch = idx & 7;                                             \
      int g = ch ^ (row & 7) ^ ((row >> 3) & 3);                                    \
      async16(vbase + (long)row * N_ + kt_ * 64 + g * 8,                            \
              vdst + (idx - lane) * 16);                                            \
    }                                                                               \
  }

  STAGE(0, 0);

  for (int kt = 0; kt < N_ / 64; ++kt) {
    const int buf = kt & 1;
    __syncthreads();                 // drains prefetch of buf (issued last iter)
    if (kt + 1 < N_ / 64) STAGE(kt + 1, buf ^ 1);

    const bf16* Kh = (const bf16*)(smem + buf * 16384) + hl * 4096;
    const bf16* Vb = (const bf16*)(smem + 32768 + buf * 16384);

    // hoisted fragments: K (2 keytiles x 4 hd-chunks), V (4 dtiles x 4 keychunks)
    bf16x8 kfrag[2][4], vfrag[4][4];
#pragma unroll
    for (int kt2 = 0; kt2 < 2; ++kt2)
#pragma unroll
      for (int c = 0; c < 4; ++c) {
        int row = kt2 * 32 + l31;
        int sw = (c * 2 + h) ^ (row & 7) ^ ((row >> 3) & 3);
        kfrag[kt2][c] = *(const bf16x8*)&Kh[row * 64 + sw * 8];
      }
#pragma unroll
    for (int dt = 0; dt < 4; ++dt)
#pragma unroll
      for (int kc = 0; kc < 4; ++kc) {
        int row = dt * 32 + l31;
        int sw = (kc * 2 + h) ^ (row & 7) ^ ((row >> 3) & 3);
        vfrag[dt][kc] = *(const bf16x8*)&Vb[row * 64 + sw * 8];
      }

    bf16x8 af[2][2];
#pragma unroll
    for (int kt2 = 0; kt2 < 2; ++kt2) {
      floatx16 sv{};
#pragma unroll
      for (int c = 0; c < 4; ++c)
        sv = __builtin_amdgcn_mfma_f32_32x32x16_bf16(kfrag[kt2][c], qf[c], sv, 0, 0, 0);
      // exp2 + row-sum
      float t[16];
      float s = 0.f;
#pragma unroll
      for (int i = 0; i < 16; ++i) { t[i] = EXP2(sv[i]); s += t[i]; }
      lp += s;
      // pack: d_i = 2 consecutive keys (reg pairs); key(reg) = (reg&3)+8*(reg>>2)+4h
      uint d0 = packbf(t[0], t[1]),   d1 = packbf(t[2], t[3]);
      uint d2 = packbf(t[4], t[5]),   d3 = packbf(t[6], t[7]);
      uint d4 = packbf(t[8], t[9]),   d5 = packbf(t[10], t[11]);
      uint d6 = packbf(t[12], t[13]), d7 = packbf(t[14], t[15]);
      uint4v f0, f1;
#if __has_builtin(__builtin_amdgcn_permlane32_swap)
      uint2v r02 = __builtin_amdgcn_permlane32_swap(d0, d2, false, false);
      uint2v r13 = __builtin_amdgcn_permlane32_swap(d1, d3, false, false);
      f0 = uint4v{r02.x, r13.x, r02.y, r13.y};
      uint2v r46 = __builtin_amdgcn_permlane32_swap(d4, d6, false, false);
      uint2v r57 = __builtin_amdgcn_permlane32_swap(d5, d7, false, false);
      f1 = uint4v{r46.x, r57.x, r46.y, r57.y};
#else
      uint e0 = __shfl_xor((int)d0, 32, 64), e1 = __shfl_xor((int)d1, 32, 64);
      uint e2 = __shfl_xor((int)d2, 32, 64), e3 = __shfl_xor((int)d3, 32, 64);
      uint e4 = __shfl_xor((int)d4, 32, 64), e5 = __shfl_xor((int)d5, 32, 64);
      uint e6 = __shfl_xor((int)d6, 32, 64), e7 = __shfl_xor((int)d7, 32, 64);
      f0 = h ? uint4v{e2, e3, d2, d3} : uint4v{d0, d1, e0, e1};
      f1 = h ? uint4v{e6, e7, d6, d7} : uint4v{d4, d5, e4, e5};
#endif
      af[kt2][0] = __builtin_bit_cast(bf16x8, f0);
      af[kt2][1] = __builtin_bit_cast(bf16x8, f1);
    }
    // O += P @ V : A = P[q=l31][k=key], B = V^T[d=l31][k=key]
#pragma unroll
    for (int dt = 0; dt < 4; ++dt)
#pragma unroll
      for (int kt2 = 0; kt2 < 2; ++kt2)
#pragma unroll
        for (int u = 0; u < 2; ++u)
          acc[dt] = __builtin_amdgcn_mfma_f32_32x32x16_bf16(
              af[kt2][u], vfrag[dt][kt2 * 2 + u], acc[dt], 0, 0, 0);
  }

  // full row-sums (both lane halves hold all keys' partials for q=l31)
  lp += __shfl_xor(lp, 32, 64);

  // K/V buffers are dead from here; overlay the fp32 O1 exchange buffer.
  float* Ob = (float*)smem;  // [128 q][128 d]
  __syncthreads();           // everyone done reading K/V before h1 overwrites

  if (hl == 1) {
#pragma unroll
    for (int r = 0; r < 16; ++r) {
      int qloc = (r & 3) + 8 * (r >> 2) + 4 * h;
      float inv = 1.0f / __shfl(lp, qloc, 64);
      float* row = &Ob[(qh * 32 + qloc) * 128 + l31];
#pragma unroll
      for (int dt = 0; dt < 4; ++dt) row[dt * 32] = acc[dt][r] * inv;
    }
  }
  __syncthreads();
  if (hl == 0) {
    // lambda = exp(lq1.lk1) - exp(lq2.lk2) + 0.8, computed in-wave (64 lanes).
    float la = lq1[lane] * lk1[lane];
    float lb = lq2[lane] * lk2[lane];
#pragma unroll
    for (int m = 1; m < 64; m <<= 1) {
      la += __shfl_xor(la, m, 64);
      lb += __shfl_xor(lb, m, 64);
    }
    float lam = __expf(la) - __expf(lb) + 0.8f;
    float nw4[4];
#pragma unroll
    for (int dt = 0; dt < 4; ++dt) nw4[dt] = norm_w[dt * 32 + l31] * 0.2f;
#pragma unroll
    for (int r = 0; r < 16; ++r) {
      int qloc = (r & 3) + 8 * (r >> 2) + 4 * h;
      float inv = 1.0f / __shfl(lp, qloc, 64);
      const float* row = &Ob[(qh * 32 + qloc) * 128 + l31];
      float v[4], ss = 0.f;
#pragma unroll
      for (int dt = 0; dt < 4; ++dt) {
        v[dt] = acc[dt][r] * inv - lam * row[dt * 32];
        ss += v[dt] * v[dt];
      }
#pragma unroll
      for (int msk = 1; msk < 32; msk <<= 1) ss += __shfl_xor(ss, msk, 64);
      float rms = rsqrtf(ss * (1.0f / 128.0f) + 1e-5f);
      int n = qbase + qh * 32 + qloc;
      bf16* dst = ao + (long)(b * N_ + n) * DIM_ + e * DV_ + l31;
#pragma unroll
      for (int dt = 0; dt < 4; ++dt) dst[dt * 32] = (bf16)(v[dt] * rms * nw4[dt]);
    }
  }
}

// ---------------- output projection GEMM -> fp32 ----------------
// 128x128 tile kept (A/B reuse), but 512 threads = 8 waves (wave 32x64):
// 2 waves/SIMD at grid 256 vs R6's 1 wave/SIMD — isolated occupancy fix.
__global__ __launch_bounds__(512) void out_gemm(
    const bf16* __restrict__ ab, const bf16* __restrict__ wo,
    const float* __restrict__ bo, float* __restrict__ out) {
  __shared__ __align__(16) bf16 At[128 * 64];
  __shared__ __align__(16) bf16 Bt[128 * 64];
  const int tid = threadIdx.x, lane = tid & 63, w = tid >> 6;
  const int tm = blockIdx.x, tn = blockIdx.y;
  const int quad = lane >> 4, l15 = lane & 15;
  const int wm = (w & 3) * 32, wn = (w >> 2) * 64;
  const bf16* Ab = ab + (long)tm * 128 * DIM_;
  const bf16* Bb = wo + (long)tn * 128 * DIM_;
  floatx4 zero = {0.f, 0.f, 0.f, 0.f};
  floatx4 acc[2][4];
#pragma unroll
  for (int i = 0; i < 2; ++i)
#pragma unroll
    for (int j = 0; j < 4; ++j) acc[i][j] = zero;

  for (int kb = 0; kb < DIM_ / 64; ++kb) {
    for (int idx = tid; idx < 1024; idx += 512) {
      int row = idx >> 3, ch = idx & 7, g = ch ^ (row & 7);
      async16(Ab + row * DIM_ + kb * 64 + g * 8, (char*)At + (idx - lane) * 16);
      async16(Bb + row * DIM_ + kb * 64 + g * 8, (char*)Bt + (idx - lane) * 16);
    }
    __syncthreads();
#pragma unroll
    for (int ks = 0; ks < 2; ++ks) {
      bf16x8 af[2], bfm[4];
#pragma unroll
      for (int mt = 0; mt < 2; ++mt) {
        int r = wm + mt * 16 + l15;
        af[mt] = *(const bf16x8*)&At[r * 64 + ((ks * 4 + quad) ^ (r & 7)) * 8];
      }
#pragma unroll
      for (int nt = 0; nt < 4; ++nt) {
        int r = wn + nt * 16 + l15;
        bfm[nt] = *(const bf16x8*)&Bt[r * 64 + ((ks * 4 + quad) ^ (r & 7)) * 8];
      }
#pragma unroll
      for (int mt = 0; mt < 2; ++mt)
#pragma unroll
        for (int nt = 0; nt < 4; ++nt)
          acc[mt][nt] = __builtin_amdgcn_mfma_f32_16x16x32_bf16(
              af[mt], bfm[nt], acc[mt][nt], 0, 0, 0);
    }
    __syncthreads();
  }
#pragma unroll
  for (int mt = 0; mt < 2; ++mt)
#pragma unroll
    for (int nt = 0; nt < 4; ++nt)
#pragma unroll
      for (int r = 0; r < 4; ++r) {
        int grow = tm * 128 + wm + mt * 16 + quad * 4 + r;
        int gcol = tn * 128 + wn + nt * 16 + l15;
        out[(long)grow * DIM_ + gcol] = acc[mt][nt][r] + bo[gcol];
      }
}

extern "C" void kernel_launch(void* const* d_in, const int* in_sizes, int n_in,
                              void* d_out, int out_size, void* d_ws, size_t ws_size,
                              hipStream_t stream) {
  const float* x    = (const float*)d_in[0];
  const float* Wq   = (const float*)d_in[1];
  const float* bq   = (const float*)d_in[2];
  const float* Wk   = (const float*)d_in[3];
  const float* bk   = (const float*)d_in[4];
  const float* Wv   = (const float*)d_in[5];
  const float* bv   = (const float*)d_in[6];
  const float* Wo   = (const float*)d_in[7];
  const float* bo   = (const float*)d_in[8];
  const float* nw   = (const float*)d_in[9];
  const float* lq1  = (const float*)d_in[10];
  const float* lk1  = (const float*)d_in[11];
  const float* lq2  = (const float*)d_in[12];
  const float* lk2  = (const float*)d_in[13];

  char* ws = (char*)d_ws;
  bf16* xb   = (bf16*)(ws + 256);              // [4096,1024] bf16
  bf16* wqb  = xb + 4194304;                   // Wq,Wk,Wv,Wo bf16 contiguous
  bf16* qb   = wqb + 4 * 1048576;              // Q scaled  [4096,1024]
  bf16* kbuf = qb + 4194304;                   // K         [4096,1024]
  bf16* vtb  = kbuf + 4194304;                 // V^T [b,e,d,key] = [16,128,2048]
  bf16* ab   = vtb + 4194304;                  // attn out  [4096,1024]

  convert_kernel<<<8192, 256, 0, stream>>>(x, Wq, Wk, Wv, Wo, xb);
  proj_kernel<<<dim3(32, 8, 3), 256, 0, stream>>>(xb, wqb, bq, bk, bv, qb, kbuf, vtb);
  attn_kernel<<<dim3(16, 8, 2), 512, 0, stream>>>(qb, kbuf, vtb, lq1, lk1, lq2, lk2,
                                                  nw, ab);
  out_gemm<<<dim3(32, 8), 512, 0, stream>>>(ab, wqb + 3 * 1048576, bo, (float*)d_out);
}

// Round 10
// 208.717 us; speedup vs baseline: 1.5668x; 1.0035x over previous
//
#include <hip/hip_runtime.h>
#include <hip/hip_bf16.h>

#define B_   2
#define N_   2048
#define DIM_ 1024
#define HD_  64
#define DV_  128

typedef __bf16 bf16;
typedef __bf16 bf16x8 __attribute__((ext_vector_type(8)));
typedef __bf16 bf16x4 __attribute__((ext_vector_type(4)));
typedef float  floatx4 __attribute__((ext_vector_type(4)));
typedef float  floatx16 __attribute__((ext_vector_type(16)));
typedef unsigned int uint;
typedef uint uint2v __attribute__((ext_vector_type(2)));
typedef uint uint4v __attribute__((ext_vector_type(4)));

#if __has_builtin(__builtin_amdgcn_exp2f)
#define EXP2(x) __builtin_amdgcn_exp2f(x)
#else
#define EXP2(x) exp2f(x)
#endif

// Q scale: hd^-0.5 (=1/8) with log2(e) folded in so softmax uses raw v_exp_f32 (2^x).
#define QSCALE 0.1803368801111244f

__device__ __forceinline__ void async16(const void* g, void* l) {
  __builtin_amdgcn_global_load_lds(
      (__attribute__((address_space(1))) void*)g,
      (__attribute__((address_space(3))) void*)l, 16, 0, 0);
}

__device__ __forceinline__ uint packbf(float a, float b) {
  unsigned short ul = __builtin_bit_cast(unsigned short, (bf16)a);
  unsigned short uh = __builtin_bit_cast(unsigned short, (bf16)b);
  return (uint)ul | ((uint)uh << 16);
}

// ---------------- convert fp32 -> bf16 (x + 4 weights, contiguous dst) ----------------
__global__ void convert_kernel(const float* __restrict__ x,
                               const float* __restrict__ wq,
                               const float* __restrict__ wk,
                               const float* __restrict__ wv,
                               const float* __restrict__ wo,
                               bf16* __restrict__ dst) {
  const int NX = B_ * N_ * DIM_;   // 4194304
  const int NW = DIM_ * DIM_;      // 1048576 = 2^20
  int i = (blockIdx.x * 256 + threadIdx.x) * 4;
  const float* src;
  int off;
  if (i < NX) { src = x; off = i; }
  else {
    int j = i - NX;
    int w = j >> 20;
    off = j & (NW - 1);
    src = (w == 0) ? wq : (w == 1) ? wk : (w == 2) ? wv : wo;
  }
  float4 v = *(const float4*)(src + off);
  bf16x4 o = { (bf16)v.x, (bf16)v.y, (bf16)v.z, (bf16)v.w };
  *(bf16x4*)(dst + i) = o;
}

// ---------------- QKV projection GEMM (z=0:Q, 1:K, 2:V-transposed) ----------------
// R19: R6/R16's proven 256-thread 128x128 kernel + the attn-proven
// double-buffered STAGE-ahead schedule (R17's BN=256 rewrite failed twice on
// container, abandoned as crash-correlated; also its byte-saving theory was
// weak — 393MB through L2 is only ~12us). Theory now: proj is latency-bound
// on the serial stage->barrier->compute chain (no prefetch overlap). Dbuf
// prefetches kb+1 while computing kb — identical schedule to attn's k-loop,
// validated over 5 rounds. No index-math changes; LDS 32->64 KB.
__global__ __launch_bounds__(256) void proj_kernel(
    const bf16* __restrict__ xb, const bf16* __restrict__ wall,
    const float* __restrict__ bq, const float* __restrict__ bk,
    const float* __restrict__ bv,
    bf16* __restrict__ qo, bf16* __restrict__ ko, bf16* __restrict__ vt) {
  __shared__ __align__(16) bf16 SM[2 * 16384];  // per buf: At 8192 | Bt 8192 elems
  const int tid = threadIdx.x, lane = tid & 63, w = tid >> 6;
  const int tm = blockIdx.x, tn = blockIdx.y, z = blockIdx.z;
  const int quad = lane >> 4, l15 = lane & 15;
  const int wm = (w >> 1) * 64, wn = (w & 1) * 64;
  const bf16* Ab = xb + (long)tm * 128 * DIM_;
  const bf16* Bb = wall + (long)z * (DIM_ * DIM_) + (long)tn * 128 * DIM_;
  floatx4 zero = {0.f, 0.f, 0.f, 0.f};
  floatx4 acc[4][4];
#pragma unroll
  for (int i = 0; i < 4; ++i)
#pragma unroll
    for (int j = 0; j < 4; ++j) acc[i][j] = zero;

#define PSTAGE(kbv, bufv)                                                           \
  {                                                                                 \
    bf16* At_ = SM + (bufv) * 16384;                                                \
    bf16* Bt_ = At_ + 8192;                                                         \
    for (int idx = tid; idx < 1024; idx += 256) {                                   \
      int row = idx >> 3, ch = idx & 7, g = ch ^ (row & 7);                         \
      async16(Ab + row * DIM_ + (kbv) * 64 + g * 8, (char*)At_ + (idx - lane) * 16);\
      async16(Bb + row * DIM_ + (kbv) * 64 + g * 8, (char*)Bt_ + (idx - lane) * 16);\
    }                                                                               \
  }

  PSTAGE(0, 0);

  for (int kb = 0; kb < DIM_ / 64; ++kb) {
    const int buf = kb & 1;
    __syncthreads();                 // drains prefetch of buf (issued last iter)
    if (kb + 1 < DIM_ / 64) PSTAGE(kb + 1, buf ^ 1);
    const bf16* At = SM + buf * 16384;
    const bf16* Bt = At + 8192;
#pragma unroll
    for (int ks = 0; ks < 2; ++ks) {
      bf16x8 af[4], bfm[4];
#pragma unroll
      for (int mt = 0; mt < 4; ++mt) {
        int r = wm + mt * 16 + l15;
        af[mt] = *(const bf16x8*)&At[r * 64 + ((ks * 4 + quad) ^ (r & 7)) * 8];
      }
#pragma unroll
      for (int nt = 0; nt < 4; ++nt) {
        int r = wn + nt * 16 + l15;
        bfm[nt] = *(const bf16x8*)&Bt[r * 64 + ((ks * 4 + quad) ^ (r & 7)) * 8];
      }
#pragma unroll
      for (int mt = 0; mt < 4; ++mt)
#pragma unroll
        for (int nt = 0; nt < 4; ++nt)
          acc[mt][nt] = __builtin_amdgcn_mfma_f32_16x16x32_bf16(
              af[mt], bfm[nt], acc[mt][nt], 0, 0, 0);
    }
  }

  if (z != 2) {
#pragma unroll
    for (int mt = 0; mt < 4; ++mt)
#pragma unroll
      for (int nt = 0; nt < 4; ++nt)
#pragma unroll
        for (int r = 0; r < 4; ++r) {
          int grow = tm * 128 + wm + mt * 16 + quad * 4 + r;
          int gcol = tn * 128 + wn + nt * 16 + l15;
          float v = acc[mt][nt][r];
          if (z == 0) {
            qo[(long)grow * DIM_ + gcol] = (bf16)((v + bq[gcol]) * QSCALE);
          } else {
            ko[(long)grow * DIM_ + gcol] = (bf16)(v + bk[gcol]);
          }
        }
  } else {
    // V epilogue: transpose through LDS, coalesced V^T row stores.
    __syncthreads();   // all waves done reading staged LDS before overlay
    bf16* Vl = SM;     // [128 d][128 keys] bf16 = 32 KB
#pragma unroll
    for (int nt = 0; nt < 4; ++nt) {
      int d = wn + nt * 16 + l15;
      float bvv = bv[tn * 128 + d];
      int m = (d & 7) * 2;
#pragma unroll
      for (int mt = 0; mt < 4; ++mt) {
        bf16x4 v4 = { (bf16)(acc[mt][nt][0] + bvv), (bf16)(acc[mt][nt][1] + bvv),
                      (bf16)(acc[mt][nt][2] + bvv), (bf16)(acc[mt][nt][3] + bvv) };
        int c = (wm >> 2) + mt * 4 + quad;
        *(bf16x4*)&Vl[d * 128 + (c ^ m) * 4] = v4;
      }
    }
    __syncthreads();
    const int bb = tm >> 4, e = tn;
    const long rowbase = ((long)(bb * 8 + e) * 128) * (long)N_ + (tm & 15) * 128;
#pragma unroll
    for (int p = 0; p < 8; ++p) {
      int d = p * 16 + (tid >> 4), j = tid & 15;
      int cs = (2 * j) ^ ((d & 7) * 2);
      bf16x8 val = *(const bf16x8*)&Vl[d * 128 + cs * 4];
      *(bf16x8*)&vt[rowbase + (long)d * N_ + j * 8] = val;
    }
  }
}

// ---------------- fused pair flash attention + diff + RMSNorm (32x32 MFMA) ------------
// R16: consolidation. R10 (512 thr, 8 waves, wave = 32q x 1 head x all keys,
// double-buffered LDS stage + one barrier/iter) measured 62.7us — every
// structural departure regressed for a measured reason:
//   R11 16 lockstep waves: pipe collision, 73us. R12 64q/wave: 117us.
//   R14 2 small blocks/CU: staging doubled, 75.6us. R15 no staging: 2KB-stride
//   gathers hit the L1 line-fetch wall (MfmaUtil 11%, 190us).
// So: R10 inner loop byte-identical. lambda computed in-epilogue.
__global__ __launch_bounds__(512, 2) void attn_kernel(
    const bf16* __restrict__ qb, const bf16* __restrict__ kbuf,
    const bf16* __restrict__ vt,
    const float* __restrict__ lq1, const float* __restrict__ lk1,
    const float* __restrict__ lq2, const float* __restrict__ lk2,
    const float* __restrict__ norm_w, bf16* __restrict__ ao) {
  __shared__ __align__(16) char smem[65536];
  // K buf: smem + buf*16384          [2 heads][64 keys][64 hd] bf16, 16 KB/buf
  // V buf: smem + 32768 + buf*16384  [128 d][64 keys] bf16, 16 KB/buf
  // Ob   : overlays everything after the k-loop: [128 q][128 d] fp32, 64 KB

  const int tid = threadIdx.x, lane = tid & 63, w = tid >> 6;
  const int qt = blockIdx.x, e = blockIdx.y, b = blockIdx.z;
  const int hl = w & 1, qh = w >> 1;     // qh in [0,4): 32-query strip
  const int h = lane >> 5, l31 = lane & 31;
  const int qbase = qt * 128;

  // Q fragments (B-operand: B[n=q=l31][k=c*16+8h+j]), loop-invariant, from global.
  bf16x8 qf[4];
  {
    const bf16* qrp = qb + (long)(b * N_ + qbase + qh * 32 + l31) * DIM_
                      + e * 128 + hl * 64 + h * 8;
#pragma unroll
    for (int c = 0; c < 4; ++c) qf[c] = *(const bf16x8*)(qrp + c * 16);
  }

  const bf16* kbase = kbuf + (long)b * N_ * DIM_ + e * 128;
  const bf16* vbase = vt + (long)(b * 8 + e) * DV_ * N_;

  floatx16 acc[4];
#pragma unroll
  for (int dt = 0; dt < 4; ++dt) acc[dt] = floatx16{};
  float lp = 0.f;  // per-lane row-sum partial, q = l31

#define STAGE(ktv, bufv)                                                            \
  {                                                                                 \
    int kt_ = (ktv);                                                                \
    char* kdst = smem + (bufv) * 16384;                                             \
    char* vdst = smem + 32768 + (bufv) * 16384;                                     \
    _Pragma("unroll") for (int t = 0; t < 2; ++t) {                                 \
      int idx = tid + t * 512;                                                      \
      int khl = idx >> 9, row = (idx >> 3) & 63, ch = idx & 7;                      \
      int g = ch ^ (row & 7) ^ ((row >> 3) & 3);                                    \
      async16(kbase + ((long)(kt_ * 64 + row)) * DIM_ + khl * 64 + g * 8,           \
              kdst + (idx - lane) * 16);                                            \
    }                                                                               \
    _Pragma("unroll") for (int t = 0; t < 2; ++t) {                                 \
      int idx = tid + t * 512;                                                      \
      int row = idx >> 3, ch = idx & 7;                                             \
      int g = ch ^ (row & 7) ^ ((row >> 3) & 3);                                    \
      async16(vbase + (long)row * N_ + kt_ * 64 + g * 8,                            \
              vdst + (idx - lane) * 16);                                            \
    }                                                                               \
  }

  STAGE(0, 0);

  for (int kt = 0; kt < N_ / 64; ++kt) {
    const int buf = kt & 1;
    __syncthreads();                 // drains prefetch of buf (issued last iter)
    if (kt + 1 < N_ / 64) STAGE(kt + 1, buf ^ 1);

    const bf16* Kh = (const bf16*)(smem + buf * 16384) + hl * 4096;
    const bf16* Vb = (const bf16*)(smem + 32768 + buf * 16384);

    // hoisted fragments: K (2 keytiles x 4 hd-chunks), V (4 dtiles x 4 keychunks)
    bf16x8 kfrag[2][4], vfrag[4][4];
#pragma unroll
    for (int kt2 = 0; kt2 < 2; ++kt2)
#pragma unroll
      for (int c = 0; c < 4; ++c) {
        int row = kt2 * 32 + l31;
        int sw = (c * 2 + h) ^ (row & 7) ^ ((row >> 3) & 3);
        kfrag[kt2][c] = *(const bf16x8*)&Kh[row * 64 + sw * 8];
      }
#pragma unroll
    for (int dt = 0; dt < 4; ++dt)
#pragma unroll
      for (int kc = 0; kc < 4; ++kc) {
        int row = dt * 32 + l31;
        int sw = (kc * 2 + h) ^ (row & 7) ^ ((row >> 3) & 3);
        vfrag[dt][kc] = *(const bf16x8*)&Vb[row * 64 + sw * 8];
      }

    bf16x8 af[2][2];
#pragma unroll
    for (int kt2 = 0; kt2 < 2; ++kt2) {
      floatx16 sv{};
#pragma unroll
      for (int c = 0; c < 4; ++c)
        sv = __builtin_amdgcn_mfma_f32_32x32x16_bf16(kfrag[kt2][c], qf[c], sv, 0, 0, 0);
      // exp2 + row-sum
      float t[16];
      float s = 0.f;
#pragma unroll
      for (int i = 0; i < 16; ++i) { t[i] = EXP2(sv[i]); s += t[i]; }
      lp += s;
      // pack: d_i = 2 consecutive keys (reg pairs); key(reg) = (reg&3)+8*(reg>>2)+4h
      uint d0 = packbf(t[0], t[1]),   d1 = packbf(t[2], t[3]);
      uint d2 = packbf(t[4], t[5]),   d3 = packbf(t[6], t[7]);
      uint d4 = packbf(t[8], t[9]),   d5 = packbf(t[10], t[11]);
      uint d6 = packbf(t[12], t[13]), d7 = packbf(t[14], t[15]);
      uint4v f0, f1;
#if __has_builtin(__builtin_amdgcn_permlane32_swap)
      uint2v r02 = __builtin_amdgcn_permlane32_swap(d0, d2, false, false);
      uint2v r13 = __builtin_amdgcn_permlane32_swap(d1, d3, false, false);
      f0 = uint4v{r02.x, r13.x, r02.y, r13.y};
      uint2v r46 = __builtin_amdgcn_permlane32_swap(d4, d6, false, false);
      uint2v r57 = __builtin_amdgcn_permlane32_swap(d5, d7, false, false);
      f1 = uint4v{r46.x, r57.x, r46.y, r57.y};
#else
      uint e0 = __shfl_xor((int)d0, 32, 64), e1 = __shfl_xor((int)d1, 32, 64);
      uint e2 = __shfl_xor((int)d2, 32, 64), e3 = __shfl_xor((int)d3, 32, 64);
      uint e4 = __shfl_xor((int)d4, 32, 64), e5 = __shfl_xor((int)d5, 32, 64);
      uint e6 = __shfl_xor((int)d6, 32, 64), e7 = __shfl_xor((int)d7, 32, 64);
      f0 = h ? uint4v{e2, e3, d2, d3} : uint4v{d0, d1, e0, e1};
      f1 = h ? uint4v{e6, e7, d6, d7} : uint4v{d4, d5, e4, e5};
#endif
      af[kt2][0] = __builtin_bit_cast(bf16x8, f0);
      af[kt2][1] = __builtin_bit_cast(bf16x8, f1);
    }
    // O += P @ V : A = P[q=l31][k=key], B = V^T[d=l31][k=key]
#pragma unroll
    for (int dt = 0; dt < 4; ++dt)
#pragma unroll
      for (int kt2 = 0; kt2 < 2; ++kt2)
#pragma unroll
        for (int u = 0; u < 2; ++u)
          acc[dt] = __builtin_amdgcn_mfma_f32_32x32x16_bf16(
              af[kt2][u], vfrag[dt][kt2 * 2 + u], acc[dt], 0, 0, 0);
  }

  // full row-sums (both lane halves hold all keys' partials for q=l31)
  lp += __shfl_xor(lp, 32, 64);

  // K/V buffers are dead from here; overlay the fp32 O1 exchange buffer.
  float* Ob = (float*)smem;  // [128 q][128 d]
  __syncthreads();           // everyone done reading K/V before h1 overwrites

  if (hl == 1) {
#pragma unroll
    for (int r = 0; r < 16; ++r) {
      int qloc = (r & 3) + 8 * (r >> 2) + 4 * h;
      float inv = 1.0f / __shfl(lp, qloc, 64);
      float* row = &Ob[(qh * 32 + qloc) * 128 + l31];
#pragma unroll
      for (int dt = 0; dt < 4; ++dt) row[dt * 32] = acc[dt][r] * inv;
    }
  }
  __syncthreads();
  if (hl == 0) {
    // lambda = exp(lq1.lk1) - exp(lq2.lk2) + 0.8, computed in-wave (64 lanes).
    float la = lq1[lane] * lk1[lane];
    float lb = lq2[lane] * lk2[lane];
#pragma unroll
    for (int m = 1; m < 64; m <<= 1) {
      la += __shfl_xor(la, m, 64);
      lb += __shfl_xor(lb, m, 64);
    }
    float lam = __expf(la) - __expf(lb) + 0.8f;
    float nw4[4];
#pragma unroll
    for (int dt = 0; dt < 4; ++dt) nw4[dt] = norm_w[dt * 32 + l31] * 0.2f;
#pragma unroll
    for (int r = 0; r < 16; ++r) {
      int qloc = (r & 3) + 8 * (r >> 2) + 4 * h;
      float inv = 1.0f / __shfl(lp, qloc, 64);
      const float* row = &Ob[(qh * 32 + qloc) * 128 + l31];
      float v[4], ss = 0.f;
#pragma unroll
      for (int dt = 0; dt < 4; ++dt) {
        v[dt] = acc[dt][r] * inv - lam * row[dt * 32];
        ss += v[dt] * v[dt];
      }
#pragma unroll
      for (int msk = 1; msk < 32; msk <<= 1) ss += __shfl_xor(ss, msk, 64);
      float rms = rsqrtf(ss * (1.0f / 128.0f) + 1e-5f);
      int n = qbase + qh * 32 + qloc;
      bf16* dst = ao + (long)(b * N_ + n) * DIM_ + e * DV_ + l31;
#pragma unroll
      for (int dt = 0; dt < 4; ++dt) dst[dt * 32] = (bf16)(v[dt] * rms * nw4[dt]);
    }
  }
}

// ---------------- output projection GEMM -> fp32 ----------------
// R19: + double-buffered STAGE-ahead (same proven schedule as attn/proj).
// 128x128 tile, 512 threads = 8 waves (wave 32x64), LDS 32->64 KB.
__global__ __launch_bounds__(512) void out_gemm(
    const bf16* __restrict__ ab, const bf16* __restrict__ wo,
    const float* __restrict__ bo, float* __restrict__ out) {
  __shared__ __align__(16) bf16 OS[2 * 16384];  // per buf: At 8192 | Bt 8192 elems
  const int tid = threadIdx.x, lane = tid & 63, w = tid >> 6;
  const int tm = blockIdx.x, tn = blockIdx.y;
  const int quad = lane >> 4, l15 = lane & 15;
  const int wm = (w & 3) * 32, wn = (w >> 2) * 64;
  const bf16* Ab = ab + (long)tm * 128 * DIM_;
  const bf16* Bb = wo + (long)tn * 128 * DIM_;
  floatx4 zero = {0.f, 0.f, 0.f, 0.f};
  floatx4 acc[2][4];
#pragma unroll
  for (int i = 0; i < 2; ++i)
#pragma unroll
    for (int j = 0; j < 4; ++j) acc[i][j] = zero;

#define OSTAGE(kbv, bufv)                                                           \
  {                                                                                 \
    bf16* At_ = OS + (bufv) * 16384;                                                \
    bf16* Bt_ = At_ + 8192;                                                         \
    for (int idx = tid; idx < 1024; idx += 512) {                                   \
      int row = idx >> 3, ch = idx & 7, g = ch ^ (row & 7);                         \
      async16(Ab + row * DIM_ + (kbv) * 64 + g * 8, (char*)At_ + (idx - lane) * 16);\
      async16(Bb + row * DIM_ + (kbv) * 64 + g * 8, (char*)Bt_ + (idx - lane) * 16);\
    }                                                                               \
  }

  OSTAGE(0, 0);

  for (int kb = 0; kb < DIM_ / 64; ++kb) {
    const int buf = kb & 1;
    __syncthreads();                 // drains prefetch of buf (issued last iter)
    if (kb + 1 < DIM_ / 64) OSTAGE(kb + 1, buf ^ 1);
    const bf16* At = OS + buf * 16384;
    const bf16* Bt = At + 8192;
#pragma unroll
    for (int ks = 0; ks < 2; ++ks) {
      bf16x8 af[2], bfm[4];
#pragma unroll
      for (int mt = 0; mt < 2; ++mt) {
        int r = wm + mt * 16 + l15;
        af[mt] = *(const bf16x8*)&At[r * 64 + ((ks * 4 + quad) ^ (r & 7)) * 8];
      }
#pragma unroll
      for (int nt = 0; nt < 4; ++nt) {
        int r = wn + nt * 16 + l15;
        bfm[nt] = *(const bf16x8*)&Bt[r * 64 + ((ks * 4 + quad) ^ (r & 7)) * 8];
      }
#pragma unroll
      for (int mt = 0; mt < 2; ++mt)
#pragma unroll
        for (int nt = 0; nt < 4; ++nt)
          acc[mt][nt] = __builtin_amdgcn_mfma_f32_16x16x32_bf16(
              af[mt], bfm[nt], acc[mt][nt], 0, 0, 0);
    }
  }
#pragma unroll
  for (int mt = 0; mt < 2; ++mt)
#pragma unroll
    for (int nt = 0; nt < 4; ++nt)
#pragma unroll
      for (int r = 0; r < 4; ++r) {
        int grow = tm * 128 + wm + mt * 16 + quad * 4 + r;
        int gcol = tn * 128 + wn + nt * 16 + l15;
        out[(long)grow * DIM_ + gcol] = acc[mt][nt][r] + bo[gcol];
      }
}

extern "C" void kernel_launch(void* const* d_in, const int* in_sizes, int n_in,
                              void* d_out, int out_size, void* d_ws, size_t ws_size,
                              hipStream_t stream) {
  const float* x    = (const float*)d_in[0];
  const float* Wq   = (const float*)d_in[1];
  const float* bq   = (const float*)d_in[2];
  const float* Wk   = (const float*)d_in[3];
  const float* bk   = (const float*)d_in[4];
  const float* Wv   = (const float*)d_in[5];
  const float* bv   = (const float*)d_in[6];
  const float* Wo   = (const float*)d_in[7];
  const float* bo   = (const float*)d_in[8];
  const float* nw   = (const float*)d_in[9];
  const float* lq1  = (const float*)d_in[10];
  const float* lk1  = (const float*)d_in[11];
  const float* lq2  = (const float*)d_in[12];
  const float* lk2  = (const float*)d_in[13];

  char* ws = (char*)d_ws;
  bf16* xb   = (bf16*)(ws + 256);              // [4096,1024] bf16
  bf16* wqb  = xb + 4194304;                   // Wq,Wk,Wv,Wo bf16 contiguous
  bf16* qb   = wqb + 4 * 1048576;              // Q scaled  [4096,1024]
  bf16* kbuf = qb + 4194304;                   // K         [4096,1024]
  bf16* vtb  = kbuf + 4194304;                 // V^T [b,e,d,key] = [16,128,2048]
  bf16* ab   = vtb + 4194304;                  // attn out  [4096,1024]

  convert_kernel<<<8192, 256, 0, stream>>>(x, Wq, Wk, Wv, Wo, xb);
  proj_kernel<<<dim3(32, 8, 3), 256, 0, stream>>>(xb, wqb, bq, bk, bv, qb, kbuf, vtb);
  attn_kernel<<<dim3(16, 8, 2), 512, 0, stream>>>(qb, kbuf, vtb, lq1, lk1, lq2, lk2,
                                                  nw, ab);
  out_gemm<<<dim3(32, 8), 512, 0, stream>>>(ab, wqb + 3 * 1048576, bo, (float*)d_out);
}